// Round 6
// baseline (275.951 us; speedup 1.0000x reference)
//
#include <hip/hip_runtime.h>
#include <cmath>

#define N_QUERY 16384
#define N_VOX   8192

// ---------------- kernel A (sums + tiny outputs) ----------------
#define A_BLOCK  512
#define A_QROWS  4
#define A_NGROUP 4            // 16 voxels per thread

// ---------------- kernel B (linear-sweep weight writer) ---------
#define B_BLOCK   256
#define B_GRID    2048
#define B_THREADS (B_BLOCK * B_GRID)            // 524288 lanes
#define B_CHUNKS  (N_QUERY * (N_VOX / 4))       // 33554432 f32x4 chunks
#define B_ITERS   (B_CHUNKS / B_THREADS)        // 64

typedef float f32x4 __attribute__((ext_vector_type(4)));

#if __has_builtin(__builtin_amdgcn_exp2f)
__device__ __forceinline__ float fast_exp2(float x) { return __builtin_amdgcn_exp2f(x); }
#else
__device__ __forceinline__ float fast_exp2(float x) { float r; asm("v_exp_f32 %0, %1" : "=v"(r) : "v"(x)); return r; }
#endif

#if __has_builtin(__builtin_amdgcn_sqrtf)
__device__ __forceinline__ float fast_sqrt(float x) { return __builtin_amdgcn_sqrtf(x); }
#else
__device__ __forceinline__ float fast_sqrt(float x) { float r; asm("v_sqrt_f32 %0, %1" : "=v"(r) : "v"(x)); return r; }
#endif

__device__ __forceinline__ float wave_reduce_sum(float v) {
    #pragma unroll
    for (int off = 32; off > 0; off >>= 1) v += __shfl_xor(v, off, 64);
    return v;
}

#define NEG_HALF_LOG2E (-0.7213475204444817f)   // -log2(e)/2  (sigma = 1)

// ============================================================
// Kernel A: per-row normalization sums + feature/size outputs.
// Writes dens/cols/sizes to d_out and inv[] (1/(sum+eps)) to d_ws.
// ============================================================
__global__ __launch_bounds__(A_BLOCK, 2)
void sums_kernel(const float* __restrict__ qp,   // [N,3]
                 const float* __restrict__ vc,   // [M,3]
                 const float* __restrict__ vf,   // [M,4]
                 const float* __restrict__ vs,   // [M]
                 float* __restrict__ dens,       // [N]
                 float* __restrict__ cols,       // [N,3]
                 float* __restrict__ sizes,      // [N]
                 float* __restrict__ inv_ws)     // [N]
{
    const int t = threadIdx.x;
    const int rowbase = blockIdx.x * A_QROWS;

    float qx[A_QROWS], qy[A_QROWS], qz[A_QROWS];
    #pragma unroll
    for (int q = 0; q < A_QROWS; ++q) {
        qx[q] = qp[(rowbase + q) * 3 + 0];
        qy[q] = qp[(rowbase + q) * 3 + 1];
        qz[q] = qp[(rowbase + q) * 3 + 2];
    }

    float asum[A_QROWS], af0[A_QROWS], af1[A_QROWS], af2[A_QROWS], af3[A_QROWS], asz[A_QROWS];
    #pragma unroll
    for (int q = 0; q < A_QROWS; ++q) {
        asum[q] = 0.f; af0[q] = 0.f; af1[q] = 0.f; af2[q] = 0.f; af3[q] = 0.f; asz[q] = 0.f;
    }

    #pragma unroll
    for (int g = 0; g < A_NGROUP; ++g) {
        const int v0 = g * (N_VOX / A_NGROUP) + t * 4;     // 16B-aligned
        const float4* cp = reinterpret_cast<const float4*>(vc + (size_t)v0 * 3);
        float4 c0 = cp[0], c1 = cp[1], c2 = cp[2];
        float cxs[4] = {c0.x, c0.w, c1.z, c2.y};
        float cys[4] = {c0.y, c1.x, c1.w, c2.z};
        float czs[4] = {c0.z, c1.y, c2.x, c2.w};
        const float4* fp = reinterpret_cast<const float4*>(vf + (size_t)v0 * 4);
        float4 fa[4] = {fp[0], fp[1], fp[2], fp[3]};
        float4 sz4 = *reinterpret_cast<const float4*>(vs + v0);
        float szs[4] = {sz4.x, sz4.y, sz4.z, sz4.w};

        #pragma unroll
        for (int i = 0; i < 4; ++i) {
            const float cx = cxs[i], cy = cys[i], cz = czs[i];
            #pragma unroll
            for (int q = 0; q < A_QROWS; ++q) {
                float dx = qx[q] - cx;
                float dy = qy[q] - cy;
                float dz = qz[q] - cz;
                float d2 = dx * dx + dy * dy + dz * dz;              // exact, >= 0
                float ww = fast_exp2(fast_sqrt(d2) * NEG_HALF_LOG2E); // exp(-d/2)
                asum[q] += ww;
                af0[q] += ww * fa[i].x;
                af1[q] += ww * fa[i].y;
                af2[q] += ww * fa[i].z;
                af3[q] += ww * fa[i].w;
                asz[q] += ww * szs[i];
            }
        }
    }

    // block reduction of 24 scalars
    float vals[A_QROWS * 6];
    #pragma unroll
    for (int q = 0; q < A_QROWS; ++q) {
        vals[q * 6 + 0] = asum[q];
        vals[q * 6 + 1] = af0[q];
        vals[q * 6 + 2] = af1[q];
        vals[q * 6 + 3] = af2[q];
        vals[q * 6 + 4] = af3[q];
        vals[q * 6 + 5] = asz[q];
    }

    __shared__ float red[A_BLOCK / 64][A_QROWS * 6];
    __shared__ float fin[A_QROWS * 6];
    const int wave = t >> 6;
    const int lane = t & 63;
    #pragma unroll
    for (int i = 0; i < A_QROWS * 6; ++i) {
        float r = wave_reduce_sum(vals[i]);
        if (lane == 0) red[wave][i] = r;
    }
    __syncthreads();
    if (t < A_QROWS * 6) {
        float s = 0.f;
        #pragma unroll
        for (int wv = 0; wv < A_BLOCK / 64; ++wv) s += red[wv][t];
        fin[t] = s;
    }
    __syncthreads();

    if (t < A_QROWS) {
        const int q = t;
        const int row = rowbase + q;
        const float iv = 1.0f / (fin[q * 6 + 0] + 1e-8f);
        const float f0 = fin[q * 6 + 1] * iv;
        const float f1 = fin[q * 6 + 2] * iv;
        const float f2 = fin[q * 6 + 3] * iv;
        const float f3 = fin[q * 6 + 4] * iv;
        const float sz = fin[q * 6 + 5] * iv;
        inv_ws[row] = iv;
        dens[row] = log1pf(expf(f0));                   // softplus
        cols[row * 3 + 0] = 1.0f / (1.0f + expf(-f1));  // sigmoid
        cols[row * 3 + 1] = 1.0f / (1.0f + expf(-f2));
        cols[row * 3 + 2] = 1.0f / (1.0f + expf(-f3));
        sizes[row] = sz;
    }
}

// ============================================================
// Kernel B: linear-sweep weight writer (fill-kernel isomorphic).
// Output is swept as consecutive f32x4 chunks, grid-stride: all
// concurrent stores land in one contiguous moving window (DRAM
// page locality). row is wave-uniform -> scalar q/inv loads.
// ============================================================
__global__ __launch_bounds__(B_BLOCK)
void weights_kernel(const float* __restrict__ qp,     // [N,3]
                    const float* __restrict__ vc,     // [M,3]
                    const float* __restrict__ inv_ws, // [N]
                    float* __restrict__ wout)         // [N,M]
{
    const int tid = blockIdx.x * B_BLOCK + threadIdx.x;   // 0..524287

    #pragma unroll 2
    for (int k = 0; k < B_ITERS; ++k) {
        const int gi = tid + k * B_THREADS;               // f32x4 chunk index
        // row = gi / (N_VOX/4) : uniform across the wave (2048 % 64 == 0)
        const int row = __builtin_amdgcn_readfirstlane(gi >> 11);
        const float qx = qp[row * 3 + 0];                 // scalar loads
        const float qy = qp[row * 3 + 1];
        const float qz = qp[row * 3 + 2];
        const float iv = inv_ws[row];

        const int v4 = gi & 2047;                         // 4-voxel group in row
        const float4* cp = reinterpret_cast<const float4*>(vc + (size_t)v4 * 12);
        float4 c0 = cp[0], c1 = cp[1], c2 = cp[2];
        const float cxs[4] = {c0.x, c0.w, c1.z, c2.y};
        const float cys[4] = {c0.y, c1.x, c1.w, c2.z};
        const float czs[4] = {c0.z, c1.y, c2.x, c2.w};

        f32x4 o;
        #pragma unroll
        for (int i = 0; i < 4; ++i) {
            float dx = qx - cxs[i];
            float dy = qy - cys[i];
            float dz = qz - czs[i];
            float d2 = dx * dx + dy * dy + dz * dz;
            float ww = fast_exp2(fast_sqrt(d2) * NEG_HALF_LOG2E);
            o[i] = ww * iv;
        }
        *reinterpret_cast<f32x4*>(wout + (size_t)gi * 4) = o;
    }
}

extern "C" void kernel_launch(void* const* d_in, const int* in_sizes, int n_in,
                              void* d_out, int out_size, void* d_ws, size_t ws_size,
                              hipStream_t stream) {
    const float* qp = (const float*)d_in[0];   // query_points [16384,3]
    const float* vc = (const float*)d_in[1];   // voxel_coords [8192,3]
    const float* vf = (const float*)d_in[2];   // voxel_features [8192,4]
    const float* vs = (const float*)d_in[3];   // voxel_sizes [8192]

    float* out   = (float*)d_out;
    float* dens  = out;                         // [16384]
    float* cols  = out + N_QUERY;               // [16384,3]
    float* sizes = out + N_QUERY * 4;           // [16384]
    float* wout  = out + N_QUERY * 5;           // [16384,8192]
    float* inv_ws = (float*)d_ws;               // [16384]

    sums_kernel<<<dim3(N_QUERY / A_QROWS), A_BLOCK, 0, stream>>>(
        qp, vc, vf, vs, dens, cols, sizes, inv_ws);

    weights_kernel<<<dim3(B_GRID), B_BLOCK, 0, stream>>>(
        qp, vc, inv_ws, wout);
}

// Round 7
// 252.971 us; speedup vs baseline: 1.0908x; 1.0908x over previous
//
#include <hip/hip_runtime.h>
#include <cmath>

#define N_QUERY 16384
#define N_VOX   8192

// ---------------- kernel A (sums + tiny outputs) ----------------
#define A_BLOCK  512
#define A_QROWS  8
#define A_NGROUP 4            // 16 voxels per thread

// ---------------- kernel B (streaming weight writer) ------------
#define B_BLOCK  256
#define B_SEG    1024         // voxels per segment = 256 threads * 4
#define B_NSEG   (N_VOX / B_SEG)   // 8
#define B_ROWS   64           // rows per block

typedef float f32x4 __attribute__((ext_vector_type(4)));

#if __has_builtin(__builtin_amdgcn_exp2f)
__device__ __forceinline__ float fast_exp2(float x) { return __builtin_amdgcn_exp2f(x); }
#else
__device__ __forceinline__ float fast_exp2(float x) { float r; asm("v_exp_f32 %0, %1" : "=v"(r) : "v"(x)); return r; }
#endif

#if __has_builtin(__builtin_amdgcn_sqrtf)
__device__ __forceinline__ float fast_sqrt(float x) { return __builtin_amdgcn_sqrtf(x); }
#else
__device__ __forceinline__ float fast_sqrt(float x) { float r; asm("v_sqrt_f32 %0, %1" : "=v"(r) : "v"(x)); return r; }
#endif

__device__ __forceinline__ float wave_reduce_sum(float v) {
    #pragma unroll
    for (int off = 32; off > 0; off >>= 1) v += __shfl_xor(v, off, 64);
    return v;
}

#define NEG_HALF_LOG2E (-0.7213475204444817f)   // -log2(e)/2  (sigma = 1)

// ============================================================
// Kernel A: per-row normalization sums + feature/size outputs.
// Writes dens/cols/sizes to d_out and inv[] (1/(sum+eps)) to d_ws.
// ============================================================
__global__ __launch_bounds__(A_BLOCK, 2)
void sums_kernel(const float* __restrict__ qp,   // [N,3]
                 const float* __restrict__ vc,   // [M,3]
                 const float* __restrict__ vf,   // [M,4]
                 const float* __restrict__ vs,   // [M]
                 float* __restrict__ dens,       // [N]
                 float* __restrict__ cols,       // [N,3]
                 float* __restrict__ sizes,      // [N]
                 float* __restrict__ inv_ws)     // [N]
{
    const int t = threadIdx.x;
    const int rowbase = blockIdx.x * A_QROWS;

    float qx[A_QROWS], qy[A_QROWS], qz[A_QROWS];
    #pragma unroll
    for (int q = 0; q < A_QROWS; ++q) {
        qx[q] = qp[(rowbase + q) * 3 + 0];
        qy[q] = qp[(rowbase + q) * 3 + 1];
        qz[q] = qp[(rowbase + q) * 3 + 2];
    }

    float asum[A_QROWS], af0[A_QROWS], af1[A_QROWS], af2[A_QROWS], af3[A_QROWS], asz[A_QROWS];
    #pragma unroll
    for (int q = 0; q < A_QROWS; ++q) {
        asum[q] = 0.f; af0[q] = 0.f; af1[q] = 0.f; af2[q] = 0.f; af3[q] = 0.f; asz[q] = 0.f;
    }

    #pragma unroll
    for (int g = 0; g < A_NGROUP; ++g) {
        const int v0 = g * (N_VOX / A_NGROUP) + t * 4;     // 16B-aligned
        const float4* cp = reinterpret_cast<const float4*>(vc + (size_t)v0 * 3);
        float4 c0 = cp[0], c1 = cp[1], c2 = cp[2];
        float cxs[4] = {c0.x, c0.w, c1.z, c2.y};
        float cys[4] = {c0.y, c1.x, c1.w, c2.z};
        float czs[4] = {c0.z, c1.y, c2.x, c2.w};
        const float4* fp = reinterpret_cast<const float4*>(vf + (size_t)v0 * 4);
        float4 fa[4] = {fp[0], fp[1], fp[2], fp[3]};
        float4 sz4 = *reinterpret_cast<const float4*>(vs + v0);
        float szs[4] = {sz4.x, sz4.y, sz4.z, sz4.w};

        #pragma unroll
        for (int i = 0; i < 4; ++i) {
            const float cx = cxs[i], cy = cys[i], cz = czs[i];
            #pragma unroll
            for (int q = 0; q < A_QROWS; ++q) {
                float dx = qx[q] - cx;
                float dy = qy[q] - cy;
                float dz = qz[q] - cz;
                float d2 = dx * dx + dy * dy + dz * dz;              // exact, >= 0
                float ww = fast_exp2(fast_sqrt(d2) * NEG_HALF_LOG2E); // exp(-d/2)
                asum[q] += ww;
                af0[q] += ww * fa[i].x;
                af1[q] += ww * fa[i].y;
                af2[q] += ww * fa[i].z;
                af3[q] += ww * fa[i].w;
                asz[q] += ww * szs[i];
            }
        }
    }

    // block reduction of 48 scalars
    float vals[A_QROWS * 6];
    #pragma unroll
    for (int q = 0; q < A_QROWS; ++q) {
        vals[q * 6 + 0] = asum[q];
        vals[q * 6 + 1] = af0[q];
        vals[q * 6 + 2] = af1[q];
        vals[q * 6 + 3] = af2[q];
        vals[q * 6 + 4] = af3[q];
        vals[q * 6 + 5] = asz[q];
    }

    __shared__ float red[A_BLOCK / 64][A_QROWS * 6];
    __shared__ float fin[A_QROWS * 6];
    const int wave = t >> 6;
    const int lane = t & 63;
    #pragma unroll
    for (int i = 0; i < A_QROWS * 6; ++i) {
        float r = wave_reduce_sum(vals[i]);
        if (lane == 0) red[wave][i] = r;
    }
    __syncthreads();
    if (t < A_QROWS * 6) {
        float s = 0.f;
        #pragma unroll
        for (int wv = 0; wv < A_BLOCK / 64; ++wv) s += red[wv][t];
        fin[t] = s;
    }
    __syncthreads();

    if (t < A_QROWS) {
        const int q = t;
        const int row = rowbase + q;
        const float iv = 1.0f / (fin[q * 6 + 0] + 1e-8f);
        const float f0 = fin[q * 6 + 1] * iv;
        const float f1 = fin[q * 6 + 2] * iv;
        const float f2 = fin[q * 6 + 3] * iv;
        const float f3 = fin[q * 6 + 4] * iv;
        const float sz = fin[q * 6 + 5] * iv;
        inv_ws[row] = iv;
        dens[row] = log1pf(expf(f0));                   // softplus
        cols[row * 3 + 0] = 1.0f / (1.0f + expf(-f1));  // sigmoid
        cols[row * 3 + 1] = 1.0f / (1.0f + expf(-f2));
        cols[row * 3 + 2] = 1.0f / (1.0f + expf(-f3));
        sizes[row] = sz;
    }
}

// ============================================================
// Kernel B: streaming weight writer — NON-TEMPORAL stores.
// Each block owns one 1024-voxel segment (coords in registers),
// loops over 64 rows. nt stores bypass L2 allocation (the two
// fastest rounds both used nt; plain stores regressed).
// ============================================================
__global__ __launch_bounds__(B_BLOCK)
void weights_kernel(const float* __restrict__ qp,     // [N,3]
                    const float* __restrict__ vc,     // [M,3]
                    const float* __restrict__ inv_ws, // [N]
                    float* __restrict__ wout)         // [N,M]
{
    const int t = threadIdx.x;
    const int seg = blockIdx.x % B_NSEG;
    const int rowtile = blockIdx.x / B_NSEG;
    const int rowbase = rowtile * B_ROWS;

    const int v0 = seg * B_SEG + t * 4;
    const float4* cp = reinterpret_cast<const float4*>(vc + (size_t)v0 * 3);
    float4 c0 = cp[0], c1 = cp[1], c2 = cp[2];
    const float cxs[4] = {c0.x, c0.w, c1.z, c2.y};
    const float cys[4] = {c0.y, c1.x, c1.w, c2.z};
    const float czs[4] = {c0.z, c1.y, c2.x, c2.w};

    #pragma unroll 4
    for (int r = 0; r < B_ROWS; ++r) {
        const int row = rowbase + r;
        const float qx = qp[row * 3 + 0];   // uniform -> scalar loads
        const float qy = qp[row * 3 + 1];
        const float qz = qp[row * 3 + 2];
        const float iv = inv_ws[row];

        f32x4 o;
        #pragma unroll
        for (int i = 0; i < 4; ++i) {
            float dx = qx - cxs[i];
            float dy = qy - cys[i];
            float dz = qz - czs[i];
            float d2 = dx * dx + dy * dy + dz * dz;
            float ww = fast_exp2(fast_sqrt(d2) * NEG_HALF_LOG2E);
            o[i] = ww * iv;
        }
        __builtin_nontemporal_store(o, reinterpret_cast<f32x4*>(wout + (size_t)row * N_VOX + v0));
    }
}

extern "C" void kernel_launch(void* const* d_in, const int* in_sizes, int n_in,
                              void* d_out, int out_size, void* d_ws, size_t ws_size,
                              hipStream_t stream) {
    const float* qp = (const float*)d_in[0];   // query_points [16384,3]
    const float* vc = (const float*)d_in[1];   // voxel_coords [8192,3]
    const float* vf = (const float*)d_in[2];   // voxel_features [8192,4]
    const float* vs = (const float*)d_in[3];   // voxel_sizes [8192]

    float* out   = (float*)d_out;
    float* dens  = out;                         // [16384]
    float* cols  = out + N_QUERY;               // [16384,3]
    float* sizes = out + N_QUERY * 4;           // [16384]
    float* wout  = out + N_QUERY * 5;           // [16384,8192]
    float* inv_ws = (float*)d_ws;               // [16384]

    sums_kernel<<<dim3(N_QUERY / A_QROWS), A_BLOCK, 0, stream>>>(
        qp, vc, vf, vs, dens, cols, sizes, inv_ws);

    weights_kernel<<<dim3(B_NSEG * (N_QUERY / B_ROWS)), B_BLOCK, 0, stream>>>(
        qp, vc, inv_ws, wout);
}

// Round 8
// 239.041 us; speedup vs baseline: 1.1544x; 1.0583x over previous
//
#include <hip/hip_runtime.h>
#include <cmath>

#define N_QUERY 16384
#define N_VOX   8192

// ---------------- kernel A (sums + tiny outputs) ----------------
#define A_BLOCK  512
#define A_QROWS  8
#define A_NGROUP 4            // 16 voxels per thread

// ---------------- kernel B (whole-row streaming writer) ---------
#define B_BLOCK  512
#define B_ROWS   8            // complete rows per block (256 KB contiguous)
#define B_NGROUP 4            // 4 strided groups of 4 voxels per thread

typedef float f32x4 __attribute__((ext_vector_type(4)));

#if __has_builtin(__builtin_amdgcn_exp2f)
__device__ __forceinline__ float fast_exp2(float x) { return __builtin_amdgcn_exp2f(x); }
#else
__device__ __forceinline__ float fast_exp2(float x) { float r; asm("v_exp_f32 %0, %1" : "=v"(r) : "v"(x)); return r; }
#endif

#if __has_builtin(__builtin_amdgcn_sqrtf)
__device__ __forceinline__ float fast_sqrt(float x) { return __builtin_amdgcn_sqrtf(x); }
#else
__device__ __forceinline__ float fast_sqrt(float x) { float r; asm("v_sqrt_f32 %0, %1" : "=v"(r) : "v"(x)); return r; }
#endif

__device__ __forceinline__ float wave_reduce_sum(float v) {
    #pragma unroll
    for (int off = 32; off > 0; off >>= 1) v += __shfl_xor(v, off, 64);
    return v;
}

#define NEG_HALF_LOG2E (-0.7213475204444817f)   // -log2(e)/2  (sigma = 1)

// ============================================================
// Kernel A: per-row normalization sums + feature/size outputs.
// Writes dens/cols/sizes to d_out and inv[] (1/(sum+eps)) to d_ws.
// ============================================================
__global__ __launch_bounds__(A_BLOCK, 2)
void sums_kernel(const float* __restrict__ qp,   // [N,3]
                 const float* __restrict__ vc,   // [M,3]
                 const float* __restrict__ vf,   // [M,4]
                 const float* __restrict__ vs,   // [M]
                 float* __restrict__ dens,       // [N]
                 float* __restrict__ cols,       // [N,3]
                 float* __restrict__ sizes,      // [N]
                 float* __restrict__ inv_ws)     // [N]
{
    const int t = threadIdx.x;
    const int rowbase = blockIdx.x * A_QROWS;

    float qx[A_QROWS], qy[A_QROWS], qz[A_QROWS];
    #pragma unroll
    for (int q = 0; q < A_QROWS; ++q) {
        qx[q] = qp[(rowbase + q) * 3 + 0];
        qy[q] = qp[(rowbase + q) * 3 + 1];
        qz[q] = qp[(rowbase + q) * 3 + 2];
    }

    float asum[A_QROWS], af0[A_QROWS], af1[A_QROWS], af2[A_QROWS], af3[A_QROWS], asz[A_QROWS];
    #pragma unroll
    for (int q = 0; q < A_QROWS; ++q) {
        asum[q] = 0.f; af0[q] = 0.f; af1[q] = 0.f; af2[q] = 0.f; af3[q] = 0.f; asz[q] = 0.f;
    }

    #pragma unroll
    for (int g = 0; g < A_NGROUP; ++g) {
        const int v0 = g * (N_VOX / A_NGROUP) + t * 4;     // 16B-aligned
        const float4* cp = reinterpret_cast<const float4*>(vc + (size_t)v0 * 3);
        float4 c0 = cp[0], c1 = cp[1], c2 = cp[2];
        float cxs[4] = {c0.x, c0.w, c1.z, c2.y};
        float cys[4] = {c0.y, c1.x, c1.w, c2.z};
        float czs[4] = {c0.z, c1.y, c2.x, c2.w};
        const float4* fp = reinterpret_cast<const float4*>(vf + (size_t)v0 * 4);
        float4 fa[4] = {fp[0], fp[1], fp[2], fp[3]};
        float4 sz4 = *reinterpret_cast<const float4*>(vs + v0);
        float szs[4] = {sz4.x, sz4.y, sz4.z, sz4.w};

        #pragma unroll
        for (int i = 0; i < 4; ++i) {
            const float cx = cxs[i], cy = cys[i], cz = czs[i];
            #pragma unroll
            for (int q = 0; q < A_QROWS; ++q) {
                float dx = qx[q] - cx;
                float dy = qy[q] - cy;
                float dz = qz[q] - cz;
                float d2 = dx * dx + dy * dy + dz * dz;              // exact, >= 0
                float ww = fast_exp2(fast_sqrt(d2) * NEG_HALF_LOG2E); // exp(-d/2)
                asum[q] += ww;
                af0[q] += ww * fa[i].x;
                af1[q] += ww * fa[i].y;
                af2[q] += ww * fa[i].z;
                af3[q] += ww * fa[i].w;
                asz[q] += ww * szs[i];
            }
        }
    }

    // block reduction of 48 scalars
    float vals[A_QROWS * 6];
    #pragma unroll
    for (int q = 0; q < A_QROWS; ++q) {
        vals[q * 6 + 0] = asum[q];
        vals[q * 6 + 1] = af0[q];
        vals[q * 6 + 2] = af1[q];
        vals[q * 6 + 3] = af2[q];
        vals[q * 6 + 4] = af3[q];
        vals[q * 6 + 5] = asz[q];
    }

    __shared__ float red[A_BLOCK / 64][A_QROWS * 6];
    __shared__ float fin[A_QROWS * 6];
    const int wave = t >> 6;
    const int lane = t & 63;
    #pragma unroll
    for (int i = 0; i < A_QROWS * 6; ++i) {
        float r = wave_reduce_sum(vals[i]);
        if (lane == 0) red[wave][i] = r;
    }
    __syncthreads();
    if (t < A_QROWS * 6) {
        float s = 0.f;
        #pragma unroll
        for (int wv = 0; wv < A_BLOCK / 64; ++wv) s += red[wv][t];
        fin[t] = s;
    }
    __syncthreads();

    if (t < A_QROWS) {
        const int q = t;
        const int row = rowbase + q;
        const float iv = 1.0f / (fin[q * 6 + 0] + 1e-8f);
        const float f0 = fin[q * 6 + 1] * iv;
        const float f1 = fin[q * 6 + 2] * iv;
        const float f2 = fin[q * 6 + 3] * iv;
        const float f3 = fin[q * 6 + 4] * iv;
        const float sz = fin[q * 6 + 5] * iv;
        inv_ws[row] = iv;
        dens[row] = log1pf(expf(f0));                   // softplus
        cols[row * 3 + 0] = 1.0f / (1.0f + expf(-f1));  // sigmoid
        cols[row * 3 + 1] = 1.0f / (1.0f + expf(-f2));
        cols[row * 3 + 2] = 1.0f / (1.0f + expf(-f3));
        sizes[row] = sz;
    }
}

// ============================================================
// Kernel B: whole-row streaming weight writer.
// Each block owns 8 COMPLETE rows (256 KB contiguous extent).
// Store pattern = R2's proven geometry: group g at v0=g*2048+t*4
// -> every store instruction is a contiguous 1 KB wave strip,
// block covers the full 32 KB row. Coords register-resident,
// all row scalars (qp, inv) hoisted to SGPRs before the loop,
// nt stores, no LDS, no barriers.
// ============================================================
__global__ __launch_bounds__(B_BLOCK)
void weights_kernel(const float* __restrict__ qp,     // [N,3]
                    const float* __restrict__ vc,     // [M,3]
                    const float* __restrict__ inv_ws, // [N]
                    float* __restrict__ wout)         // [N,M]
{
    const int t = threadIdx.x;
    const int rowbase = blockIdx.x * B_ROWS;

    // ---- coords for this thread's 16 voxels (4 strided groups of 4) ----
    float cxs[B_NGROUP][4], cys[B_NGROUP][4], czs[B_NGROUP][4];
    #pragma unroll
    for (int g = 0; g < B_NGROUP; ++g) {
        const int v0 = g * (N_VOX / B_NGROUP) + t * 4;
        const float4* cp = reinterpret_cast<const float4*>(vc + (size_t)v0 * 3);
        float4 c0 = cp[0], c1 = cp[1], c2 = cp[2];
        cxs[g][0] = c0.x; cxs[g][1] = c0.w; cxs[g][2] = c1.z; cxs[g][3] = c2.y;
        cys[g][0] = c0.y; cys[g][1] = c1.x; cys[g][2] = c1.w; cys[g][3] = c2.z;
        czs[g][0] = c0.z; czs[g][1] = c1.y; czs[g][2] = c2.x; czs[g][3] = c2.w;
    }

    // ---- hoist all row scalars (uniform -> SGPR batch) ----
    float rqx[B_ROWS], rqy[B_ROWS], rqz[B_ROWS], riv[B_ROWS];
    #pragma unroll
    for (int r = 0; r < B_ROWS; ++r) {
        rqx[r] = qp[(rowbase + r) * 3 + 0];
        rqy[r] = qp[(rowbase + r) * 3 + 1];
        rqz[r] = qp[(rowbase + r) * 3 + 2];
        riv[r] = inv_ws[rowbase + r];
    }

    // ---- 8 rows x 4 strips: every store = contiguous 1 KB wave strip ----
    #pragma unroll 2
    for (int r = 0; r < B_ROWS; ++r) {
        const float qx = rqx[r], qy = rqy[r], qz = rqz[r], iv = riv[r];
        float* base = wout + (size_t)(rowbase + r) * N_VOX;
        #pragma unroll
        for (int g = 0; g < B_NGROUP; ++g) {
            const int v0 = g * (N_VOX / B_NGROUP) + t * 4;
            f32x4 o;
            #pragma unroll
            for (int i = 0; i < 4; ++i) {
                float dx = qx - cxs[g][i];
                float dy = qy - cys[g][i];
                float dz = qz - czs[g][i];
                float d2 = dx * dx + dy * dy + dz * dz;
                float ww = fast_exp2(fast_sqrt(d2) * NEG_HALF_LOG2E);
                o[i] = ww * iv;
            }
            __builtin_nontemporal_store(o, reinterpret_cast<f32x4*>(base + v0));
        }
    }
}

extern "C" void kernel_launch(void* const* d_in, const int* in_sizes, int n_in,
                              void* d_out, int out_size, void* d_ws, size_t ws_size,
                              hipStream_t stream) {
    const float* qp = (const float*)d_in[0];   // query_points [16384,3]
    const float* vc = (const float*)d_in[1];   // voxel_coords [8192,3]
    const float* vf = (const float*)d_in[2];   // voxel_features [8192,4]
    const float* vs = (const float*)d_in[3];   // voxel_sizes [8192]

    float* out   = (float*)d_out;
    float* dens  = out;                         // [16384]
    float* cols  = out + N_QUERY;               // [16384,3]
    float* sizes = out + N_QUERY * 4;           // [16384]
    float* wout  = out + N_QUERY * 5;           // [16384,8192]
    float* inv_ws = (float*)d_ws;               // [16384]

    sums_kernel<<<dim3(N_QUERY / A_QROWS), A_BLOCK, 0, stream>>>(
        qp, vc, vf, vs, dens, cols, sizes, inv_ws);

    weights_kernel<<<dim3(N_QUERY / B_ROWS), B_BLOCK, 0, stream>>>(
        qp, vc, inv_ws, wout);
}

// Round 9
// 216.724 us; speedup vs baseline: 1.2733x; 1.1030x over previous
//
#include <hip/hip_runtime.h>
#include <cmath>

#define N_QUERY 16384
#define N_VOX   8192
#define Q_ROWS  4          // query rows per block
#define BLOCK   512        // threads per block (8 waves)
#define VPT     16         // voxels per thread = N_VOX / BLOCK
#define NGROUP  4          // groups of 4 voxels per thread (VPT/4)

typedef float f32x4 __attribute__((ext_vector_type(4)));

#if __has_builtin(__builtin_amdgcn_exp2f)
__device__ __forceinline__ float fast_exp2(float x) { return __builtin_amdgcn_exp2f(x); }
#else
__device__ __forceinline__ float fast_exp2(float x) { float r; asm("v_exp_f32 %0, %1" : "=v"(r) : "v"(x)); return r; }
#endif

#if __has_builtin(__builtin_amdgcn_sqrtf)
__device__ __forceinline__ float fast_sqrt(float x) { return __builtin_amdgcn_sqrtf(x); }
#else
__device__ __forceinline__ float fast_sqrt(float x) { float r; asm("v_sqrt_f32 %0, %1" : "=v"(r) : "v"(x)); return r; }
#endif

__device__ __forceinline__ float wave_reduce_sum(float v) {
    #pragma unroll
    for (int off = 32; off > 0; off >>= 1) v += __shfl_xor(v, off, 64);
    return v;
}

__global__ __launch_bounds__(BLOCK)
void voxel_interp_kernel(const float* __restrict__ qp,   // [N,3]
                         const float* __restrict__ vc,   // [M,3]
                         const float* __restrict__ vf,   // [M,4]
                         const float* __restrict__ vs,   // [M]
                         float* __restrict__ dens,       // [N]
                         float* __restrict__ cols,       // [N,3]
                         float* __restrict__ sizes,      // [N]
                         float* __restrict__ wout)       // [N,M]
{
    const int t = threadIdx.x;
    const int rowbase = blockIdx.x * Q_ROWS;

    // ---- load the Q query points (uniform across block -> scalar loads) ----
    float qx[Q_ROWS], qy[Q_ROWS], qz[Q_ROWS];
    #pragma unroll
    for (int q = 0; q < Q_ROWS; ++q) {
        qx[q] = qp[(rowbase + q) * 3 + 0];
        qy[q] = qp[(rowbase + q) * 3 + 1];
        qz[q] = qp[(rowbase + q) * 3 + 2];
    }

    float w[Q_ROWS][VPT];                 // unnormalized weights (registers)
    float asum[Q_ROWS];
    float af0[Q_ROWS], af1[Q_ROWS], af2[Q_ROWS], af3[Q_ROWS];
    float asz[Q_ROWS];
    #pragma unroll
    for (int q = 0; q < Q_ROWS; ++q) {
        asum[q] = 0.f; af0[q] = 0.f; af1[q] = 0.f; af2[q] = 0.f; af3[q] = 0.f; asz[q] = 0.f;
    }

    const float NEG_HALF_LOG2E = -0.7213475204444817f;  // -log2(e)/2  (sigma=1)

    // ---- main pass: each thread owns 4 groups of 4 consecutive voxels ----
    #pragma unroll
    for (int g = 0; g < NGROUP; ++g) {
        const int v0 = g * (N_VOX / NGROUP) + t * 4;   // 16B-aligned everywhere
        // 4 voxels * 3 coords = 12 contiguous floats -> 3x float4
        const float4* cp = reinterpret_cast<const float4*>(vc + (size_t)v0 * 3);
        float4 c0 = cp[0], c1 = cp[1], c2 = cp[2];
        float cxs[4] = {c0.x, c0.w, c1.z, c2.y};
        float cys[4] = {c0.y, c1.x, c1.w, c2.z};
        float czs[4] = {c0.z, c1.y, c2.x, c2.w};
        const float4* fp = reinterpret_cast<const float4*>(vf + (size_t)v0 * 4);
        float4 fa[4] = {fp[0], fp[1], fp[2], fp[3]};
        float4 sz4 = *reinterpret_cast<const float4*>(vs + v0);
        float szs[4] = {sz4.x, sz4.y, sz4.z, sz4.w};

        #pragma unroll
        for (int i = 0; i < 4; ++i) {
            const float cx = cxs[i], cy = cys[i], cz = czs[i];
            #pragma unroll
            for (int q = 0; q < Q_ROWS; ++q) {
                float dx = qx[q] - cx;
                float dy = qy[q] - cy;
                float dz = qz[q] - cz;
                float d2 = dx * dx + dy * dy + dz * dz;   // exact, >= 0
                float d  = fast_sqrt(d2);
                float ww = fast_exp2(d * NEG_HALF_LOG2E); // exp(-d/2)
                w[q][g * 4 + i] = ww;
                asum[q] += ww;
                af0[q] += ww * fa[i].x;
                af1[q] += ww * fa[i].y;
                af2[q] += ww * fa[i].z;
                af3[q] += ww * fa[i].w;
                asz[q] += ww * szs[i];
            }
        }
    }

    // ---- block reduction of 24 values (sum, f0..f3, size) x Q_ROWS ----
    float vals[Q_ROWS * 6];
    #pragma unroll
    for (int q = 0; q < Q_ROWS; ++q) {
        vals[q * 6 + 0] = asum[q];
        vals[q * 6 + 1] = af0[q];
        vals[q * 6 + 2] = af1[q];
        vals[q * 6 + 3] = af2[q];
        vals[q * 6 + 4] = af3[q];
        vals[q * 6 + 5] = asz[q];
    }

    __shared__ float red[BLOCK / 64][Q_ROWS * 6];
    __shared__ float fin[Q_ROWS * 6];
    const int wave = t >> 6;
    const int lane = t & 63;
    #pragma unroll
    for (int i = 0; i < Q_ROWS * 6; ++i) {
        float r = wave_reduce_sum(vals[i]);
        if (lane == 0) red[wave][i] = r;
    }
    __syncthreads();
    if (t < Q_ROWS * 6) {
        float s = 0.f;
        #pragma unroll
        for (int wv = 0; wv < BLOCK / 64; ++wv) s += red[wv][t];
        fin[t] = s;
    }
    __syncthreads();

    float inv[Q_ROWS];
    #pragma unroll
    for (int q = 0; q < Q_ROWS; ++q) {
        inv[q] = 1.0f / (fin[q * 6 + 0] + 1e-8f);   // LDS broadcast read
    }

    // ---- streaming write of normalized weights (PLAIN writeback float4) ----
    #pragma unroll
    for (int q = 0; q < Q_ROWS; ++q) {
        const float iv = inv[q];
        float* base = wout + (size_t)(rowbase + q) * N_VOX;
        #pragma unroll
        for (int g = 0; g < NGROUP; ++g) {
            const int v0 = g * (N_VOX / NGROUP) + t * 4;
            f32x4 o;
            o.x = w[q][g * 4 + 0] * iv;
            o.y = w[q][g * 4 + 1] * iv;
            o.z = w[q][g * 4 + 2] * iv;
            o.w = w[q][g * 4 + 3] * iv;
            *reinterpret_cast<f32x4*>(base + v0) = o;
        }
    }

    // ---- tiny per-row outputs ----
    if (t < Q_ROWS) {
        const int q = t;
        const int row = rowbase + q;
        const float iv = inv[q];
        const float f0 = fin[q * 6 + 1] * iv;
        const float f1 = fin[q * 6 + 2] * iv;
        const float f2 = fin[q * 6 + 3] * iv;
        const float f3 = fin[q * 6 + 4] * iv;
        const float sz = fin[q * 6 + 5] * iv;
        dens[row] = log1pf(expf(f0));                 // softplus
        cols[row * 3 + 0] = 1.0f / (1.0f + expf(-f1));  // sigmoid
        cols[row * 3 + 1] = 1.0f / (1.0f + expf(-f2));
        cols[row * 3 + 2] = 1.0f / (1.0f + expf(-f3));
        sizes[row] = sz;
    }
}

extern "C" void kernel_launch(void* const* d_in, const int* in_sizes, int n_in,
                              void* d_out, int out_size, void* d_ws, size_t ws_size,
                              hipStream_t stream) {
    const float* qp = (const float*)d_in[0];   // query_points [16384,3]
    const float* vc = (const float*)d_in[1];   // voxel_coords [8192,3]
    const float* vf = (const float*)d_in[2];   // voxel_features [8192,4]
    const float* vs = (const float*)d_in[3];   // voxel_sizes [8192]

    float* out   = (float*)d_out;
    float* dens  = out;                         // [16384]
    float* cols  = out + N_QUERY;               // [16384,3]
    float* sizes = out + N_QUERY * 4;           // [16384]
    float* wout  = out + N_QUERY * 5;           // [16384,8192]

    dim3 grid(N_QUERY / Q_ROWS);
    voxel_interp_kernel<<<grid, BLOCK, 0, stream>>>(qp, vc, vf, vs, dens, cols, sizes, wout);
}